// Round 12
// baseline (148.666 us; speedup 1.0000x reference)
//
#include <hip/hip_runtime.h>

#define NF    256   // IN_F
#define HD    256   // H*D
#define NH    4
#define DH    64
#define WINS  128   // WIN
#define HALFW 64
#define TOPK  32
#define GROWS 16    // rows per gemm block (4 waves x 4 rows) -> 2 waves/SIMD

// ------------- fused Q/K projection: X[n,256] @ W[256,256] + b -------------
// grid (n/16, 2) = 512 blocks -> 2 blocks/CU, 2 waves/SIMD. Wave = 4 rows;
// lane owns cols 4l..4l+3. Explicit 2-stage register pipeline on W (R11's,
// which measured -7us): next k-group's 8 b128 loads issued before consuming
// current group. X via wave-uniform s_loads. Row-major coalesced stores.
__global__ __launch_bounds__(256) void qk_gemm_kernel(
    const float* __restrict__ X,
    const float* __restrict__ Wq, const float* __restrict__ bq,
    const float* __restrict__ Wk, const float* __restrict__ bk,
    float* __restrict__ Qb, float* __restrict__ Kb, int n)
{
    const int t    = threadIdx.x;
    const int wave = t >> 6;
    const int lane = t & 63;
    const bool isK = (blockIdx.y != 0);
    const float* W   = isK ? Wk : Wq;
    const float* bia = isK ? bk : bq;
    float*       Out = isK ? Kb : Qb;

    const int r0  = blockIdx.x * GROWS + wave * 4;
    const int r0s = __builtin_amdgcn_readfirstlane(r0);
    const float* Xs = X + (size_t)r0s * NF;        // scalar base -> s_load

    float4 acc[4];
#pragma unroll
    for (int r = 0; r < 4; ++r) acc[r] = make_float4(0.f, 0.f, 0.f, 0.f);

    float4 wA[8], wB[8];
    const float* Wl = W + 4 * lane;

#pragma unroll
    for (int u = 0; u < 8; ++u)                     // prologue: group 0
        wA[u] = *(const float4*)(Wl + (size_t)u * HD);

    for (int k = 0; k < NF; k += 16) {
        if (k + 8 < NF) {
#pragma unroll
            for (int u = 0; u < 8; ++u)             // prefetch group g+1
                wB[u] = *(const float4*)(Wl + (size_t)(k + 8 + u) * HD);
        }
#pragma unroll
        for (int u = 0; u < 8; ++u) {
#pragma unroll
            for (int r = 0; r < 4; ++r) {
                float xk = Xs[r * NF + k + u];      // SGPR broadcast
                acc[r].x += xk * wA[u].x;
                acc[r].y += xk * wA[u].y;
                acc[r].z += xk * wA[u].z;
                acc[r].w += xk * wA[u].w;
            }
        }
        if (k + 16 < NF) {
#pragma unroll
            for (int u = 0; u < 8; ++u)             // prefetch group g+2
                wA[u] = *(const float4*)(Wl + (size_t)(k + 16 + u) * HD);
        }
#pragma unroll
        for (int u = 0; u < 8; ++u) {
#pragma unroll
            for (int r = 0; r < 4; ++r) {
                float xk = Xs[r * NF + k + 8 + u];  // SGPR broadcast
                acc[r].x += xk * wB[u].x;
                acc[r].y += xk * wB[u].y;
                acc[r].z += xk * wB[u].z;
                acc[r].w += xk * wB[u].w;
            }
        }
    }

    const float4 bv = *(const float4*)(bia + 4 * lane);
#pragma unroll
    for (int r = 0; r < 4; ++r) {
        acc[r].x += bv.x; acc[r].y += bv.y; acc[r].z += bv.z; acc[r].w += bv.w;
        *(float4*)(Out + (size_t)(r0 + r) * HD + 4 * lane) = acc[r];  // coalesced
    }
}

// ---- per-node windowed attention + top-32 + fused full-row write ----
// R3/R10 measured-best structure, widened to 512 threads (8 waves): score
// rows and the row write split 8 ways for better latency overlap.
__global__ __launch_bounds__(512) void attn_topk_kernel(
    const float* __restrict__ Q,
    const float* __restrict__ K,
    const int* __restrict__ nnpg, int n_graphs,
    const int* __restrict__ nrel,
    float* __restrict__ out, int n)
{
    const int i    = blockIdx.x;
    const int t    = threadIdx.x;
    const int wave = t >> 6;
    const int lane = t & 63;

    __shared__ float sc[NH][WINS];     // per-head scores (0 for padded slots)
    __shared__ float pr[NH][WINS];     // per-head softmax probs
    __shared__ float attnv[WINS];
    __shared__ float slotval[WINS];

    // segment bounds: tile(nnpg, R) -> cumsum -> searchsorted(right)
    int R = nrel[0];
    int total = n_graphs * R;
    int seg_start = 0, seg_end = n;
    int cum = 0;
    for (int e = 0; e < total; ++e) {
        int sz = nnpg[e % n_graphs];
        int nc = cum + sz;
        if (i < nc) { seg_start = cum; seg_end = nc; break; }
        cum = nc;
    }
    const int start = max(seg_start, i - HALFW);
    const int end   = min(seg_end,   i + HALFW);
    const int win   = end - start;            // >= 64 (segments >= 128 nodes)

    // lane's Q chunk: dims [4*lane, 4*lane+4), head = lane>>4
    const float4 q4 = *(const float4*)(Q + (size_t)i * HD + lane * 4);

    // ---- scores: wave w handles rows {w + 8j}; 8-deep independent loads ----
#pragma unroll 8
    for (int j = 0; j < 16; ++j) {
        int row = wave + 8 * j;               // 0..127
        float v = 0.f;
        if (row < win) {
            float4 k4 = *(const float4*)(K + (size_t)(start + row) * HD + lane * 4);
            v = q4.x * k4.x + q4.y * k4.y + q4.z * k4.z + q4.w * k4.w;
        }
        v += __shfl_xor(v, 1);
        v += __shfl_xor(v, 2);
        v += __shfl_xor(v, 4);
        v += __shfl_xor(v, 8);
        if ((lane & 15) == 0)
            sc[lane >> 4][row] = v * 0.25f;   // /sqrt(64)/tau; padded rows -> 0
    }
    __syncthreads();

    // ---- per-head softmax over full 128-slot window: waves 0-3 = heads ----
    if (wave < NH) {
        float v0 = sc[wave][lane], v1 = sc[wave][lane + 64];
        float mx = fmaxf(v0, v1);
#pragma unroll
        for (int off = 32; off > 0; off >>= 1) mx = fmaxf(mx, __shfl_xor(mx, off));
        float e0 = expf(v0 - mx), e1 = expf(v1 - mx);
        float sm = e0 + e1;
#pragma unroll
        for (int off = 32; off > 0; off >>= 1) sm += __shfl_xor(sm, off);
        pr[wave][lane]      = e0 / sm;
        pr[wave][lane + 64] = e1 / sm;
    }
    __syncthreads();

    // ---- mean over heads; invalid slots excluded from top-k ----
    if (t < WINS) {
        float a = 0.25f * (pr[0][t] + pr[1][t] + pr[2][t] + pr[3][t]);
        attnv[t] = (t < win) ? a : -1.0f;
    }
    __syncthreads();

    // ---- stable top-32 rank count (lower index wins ties, like lax.top_k) ----
    if (t < WINS) {
        float v = attnv[t];
        int cnt = 0;
#pragma unroll
        for (int j4 = 0; j4 < WINS / 4; ++j4) {
            float4 a4 = *(const float4*)&attnv[j4 * 4];
            int jb = j4 * 4;
            cnt += (a4.x > v) || (a4.x == v && (jb + 0) < t);
            cnt += (a4.y > v) || (a4.y == v && (jb + 1) < t);
            cnt += (a4.z > v) || (a4.z == v && (jb + 2) < t);
            cnt += (a4.w > v) || (a4.w == v && (jb + 3) < t);
        }
        slotval[t] = (t < win && cnt < TOPK) ? 1.0f : 0.0f;
    }
    __syncthreads();

    // ---- fused full-row write: zeros + window values, float4 stores ----
    float4* orow = (float4*)(out + (size_t)i * n);
    const int n4 = n >> 2;
    for (int c4 = t; c4 < n4; c4 += 512) {
        int c = c4 << 2;
        float4 v4 = make_float4(0.f, 0.f, 0.f, 0.f);
        if (c + 3 >= start && c < end) {
            int o = c - start;
            if (o     >= 0 && o     < WINS) v4.x = slotval[o];
            if (o + 1 >= 0 && o + 1 < WINS) v4.y = slotval[o + 1];
            if (o + 2 >= 0 && o + 2 < WINS) v4.z = slotval[o + 2];
            if (o + 3 >= 0 && o + 3 < WINS) v4.w = slotval[o + 3];
        }
        orow[c4] = v4;
    }
}

extern "C" void kernel_launch(void* const* d_in, const int* in_sizes, int n_in,
                              void* d_out, int out_size, void* d_ws, size_t ws_size,
                              hipStream_t stream)
{
    const float* X  = (const float*)d_in[0];
    const float* Wq = (const float*)d_in[1];
    const float* bq = (const float*)d_in[2];
    const float* Wk = (const float*)d_in[3];
    const float* bk = (const float*)d_in[4];
    const int* nnpg = (const int*)d_in[5];
    const int* nrel = (const int*)d_in[6];

    const int n = in_sizes[0] / NF;
    const int n_graphs = in_sizes[5];

    float* Qb = (float*)d_ws;                 // [n][256]
    float* Kb = Qb + (size_t)n * HD;          // [n][256]
    float* out = (float*)d_out;

    dim3 gg(n / GROWS, 2);
    qk_gemm_kernel<<<gg, 256, 0, stream>>>(X, Wq, bq, Wk, bk, Qb, Kb, n);

    attn_topk_kernel<<<n, 512, 0, stream>>>(Qb, Kb, nnpg, n_graphs, nrel, out, n);
}

// Round 13
// 148.336 us; speedup vs baseline: 1.0022x; 1.0022x over previous
//
#include <hip/hip_runtime.h>

#define NF    256   // IN_F
#define HD    256   // H*D
#define NH    4
#define DH    64
#define WINS  128   // WIN
#define HALFW 64
#define TOPK  32
#define GROWS 32    // rows per gemm block (8 waves x 4 rows)

// ------------- fused Q/K projection: X[n,256] @ W[256,256] + b -------------
// grid (n/32, 2) = 256 blocks, 512 threads -> 1 block/CU, 2 waves/SIMD.
// Wave = 4 rows; lane owns cols 4l..4l+3. 2-stage register pipeline on BOTH
// W (VGPR b128 loads) and X (SGPR wave-uniform s_loads): group g+1's loads
// are issued before group g's FMAs, so vmcnt/lgkmcnt waits overlap compute.
__global__ __launch_bounds__(512) void qk_gemm_kernel(
    const float* __restrict__ X,
    const float* __restrict__ Wq, const float* __restrict__ bq,
    const float* __restrict__ Wk, const float* __restrict__ bk,
    float* __restrict__ Qb, float* __restrict__ Kb, int n)
{
    const int t    = threadIdx.x;
    const int wave = t >> 6;
    const int lane = t & 63;
    const bool isK = (blockIdx.y != 0);
    const float* W   = isK ? Wk : Wq;
    const float* bia = isK ? bk : bq;
    float*       Out = isK ? Kb : Qb;

    const int r0  = blockIdx.x * GROWS + wave * 4;
    const int r0s = __builtin_amdgcn_readfirstlane(r0);
    const float* Xs = X + (size_t)r0s * NF;        // scalar base -> s_load

    float4 acc[4];
#pragma unroll
    for (int r = 0; r < 4; ++r) acc[r] = make_float4(0.f, 0.f, 0.f, 0.f);

    float4 wA[8], wB[8];
    float  xA[4][8], xB[4][8];
    const float* Wl = W + 4 * lane;

    // prologue: stage k-group 0 (W into VGPRs, X into SGPRs)
#pragma unroll
    for (int u = 0; u < 8; ++u)
        wA[u] = *(const float4*)(Wl + (size_t)u * HD);
#pragma unroll
    for (int r = 0; r < 4; ++r)
#pragma unroll
        for (int u = 0; u < 8; ++u)
            xA[r][u] = Xs[r * NF + u];

    for (int k = 0; k < NF; k += 16) {
        if (k + 8 < NF) {                           // prefetch group g+1
#pragma unroll
            for (int u = 0; u < 8; ++u)
                wB[u] = *(const float4*)(Wl + (size_t)(k + 8 + u) * HD);
#pragma unroll
            for (int r = 0; r < 4; ++r)
#pragma unroll
                for (int u = 0; u < 8; ++u)
                    xB[r][u] = Xs[r * NF + k + 8 + u];
        }
#pragma unroll
        for (int u = 0; u < 8; ++u) {
#pragma unroll
            for (int r = 0; r < 4; ++r) {
                float xk = xA[r][u];
                acc[r].x += xk * wA[u].x;
                acc[r].y += xk * wA[u].y;
                acc[r].z += xk * wA[u].z;
                acc[r].w += xk * wA[u].w;
            }
        }
        if (k + 16 < NF) {                          // prefetch group g+2
#pragma unroll
            for (int u = 0; u < 8; ++u)
                wA[u] = *(const float4*)(Wl + (size_t)(k + 16 + u) * HD);
#pragma unroll
            for (int r = 0; r < 4; ++r)
#pragma unroll
                for (int u = 0; u < 8; ++u)
                    xA[r][u] = Xs[r * NF + k + 16 + u];
        }
#pragma unroll
        for (int u = 0; u < 8; ++u) {
#pragma unroll
            for (int r = 0; r < 4; ++r) {
                float xk = xB[r][u];
                acc[r].x += xk * wB[u].x;
                acc[r].y += xk * wB[u].y;
                acc[r].z += xk * wB[u].z;
                acc[r].w += xk * wB[u].w;
            }
        }
    }

    const float4 bv = *(const float4*)(bia + 4 * lane);
#pragma unroll
    for (int r = 0; r < 4; ++r) {
        acc[r].x += bv.x; acc[r].y += bv.y; acc[r].z += bv.z; acc[r].w += bv.w;
        *(float4*)(Out + (size_t)(r0 + r) * HD + 4 * lane) = acc[r];  // coalesced
    }
}

// ---- per-node windowed attention + top-32 + fused full-row write ----
// (R10's exact kernel — measured 53.5us three times incl. the 64MiB write)
__global__ __launch_bounds__(256) void attn_topk_kernel(
    const float* __restrict__ Q,
    const float* __restrict__ K,
    const int* __restrict__ nnpg, int n_graphs,
    const int* __restrict__ nrel,
    float* __restrict__ out, int n)
{
    const int i    = blockIdx.x;
    const int t    = threadIdx.x;
    const int wave = t >> 6;
    const int lane = t & 63;

    __shared__ float sc[NH][WINS];     // per-head scores (0 for padded slots)
    __shared__ float pr[NH][WINS];     // per-head softmax probs
    __shared__ float attnv[WINS];
    __shared__ float slotval[WINS];

    // segment bounds: tile(nnpg, R) -> cumsum -> searchsorted(right)
    int R = nrel[0];
    int total = n_graphs * R;
    int seg_start = 0, seg_end = n;
    int cum = 0;
    for (int e = 0; e < total; ++e) {
        int sz = nnpg[e % n_graphs];
        int nc = cum + sz;
        if (i < nc) { seg_start = cum; seg_end = nc; break; }
        cum = nc;
    }
    const int start = max(seg_start, i - HALFW);
    const int end   = min(seg_end,   i + HALFW);
    const int win   = end - start;            // >= 64 (segments >= 128 nodes)

    // lane's Q chunk: dims [4*lane, 4*lane+4), head = lane>>4
    const float4 q4 = *(const float4*)(Q + (size_t)i * HD + lane * 4);

    // ---- scores: wave w handles rows {w + 4j}; 8-deep independent loads ----
#pragma unroll 8
    for (int j = 0; j < 32; ++j) {
        int row = wave + 4 * j;               // 0..127
        float v = 0.f;
        if (row < win) {
            float4 k4 = *(const float4*)(K + (size_t)(start + row) * HD + lane * 4);
            v = q4.x * k4.x + q4.y * k4.y + q4.z * k4.z + q4.w * k4.w;
        }
        v += __shfl_xor(v, 1);
        v += __shfl_xor(v, 2);
        v += __shfl_xor(v, 4);
        v += __shfl_xor(v, 8);
        if ((lane & 15) == 0)
            sc[lane >> 4][row] = v * 0.25f;   // /sqrt(64)/tau; padded rows -> 0
    }
    __syncthreads();

    // ---- per-head softmax over full 128-slot window: wave w = head w ----
    {
        float v0 = sc[wave][lane], v1 = sc[wave][lane + 64];
        float mx = fmaxf(v0, v1);
#pragma unroll
        for (int off = 32; off > 0; off >>= 1) mx = fmaxf(mx, __shfl_xor(mx, off));
        float e0 = expf(v0 - mx), e1 = expf(v1 - mx);
        float sm = e0 + e1;
#pragma unroll
        for (int off = 32; off > 0; off >>= 1) sm += __shfl_xor(sm, off);
        pr[wave][lane]      = e0 / sm;
        pr[wave][lane + 64] = e1 / sm;
    }
    __syncthreads();

    // ---- mean over heads; invalid slots excluded from top-k ----
    if (t < WINS) {
        float a = 0.25f * (pr[0][t] + pr[1][t] + pr[2][t] + pr[3][t]);
        attnv[t] = (t < win) ? a : -1.0f;
    }
    __syncthreads();

    // ---- stable top-32 rank count (lower index wins ties, like lax.top_k) ----
    if (t < WINS) {
        float v = attnv[t];
        int cnt = 0;
#pragma unroll
        for (int j4 = 0; j4 < WINS / 4; ++j4) {
            float4 a4 = *(const float4*)&attnv[j4 * 4];
            int jb = j4 * 4;
            cnt += (a4.x > v) || (a4.x == v && (jb + 0) < t);
            cnt += (a4.y > v) || (a4.y == v && (jb + 1) < t);
            cnt += (a4.z > v) || (a4.z == v && (jb + 2) < t);
            cnt += (a4.w > v) || (a4.w == v && (jb + 3) < t);
        }
        slotval[t] = (t < win && cnt < TOPK) ? 1.0f : 0.0f;
    }
    __syncthreads();

    // ---- fused full-row write: zeros + window values, float4 stores ----
    float4* orow = (float4*)(out + (size_t)i * n);
    const int n4 = n >> 2;
    for (int c4 = t; c4 < n4; c4 += 256) {
        int c = c4 << 2;
        float4 v4 = make_float4(0.f, 0.f, 0.f, 0.f);
        if (c + 3 >= start && c < end) {
            int o = c - start;
            if (o     >= 0 && o     < WINS) v4.x = slotval[o];
            if (o + 1 >= 0 && o + 1 < WINS) v4.y = slotval[o + 1];
            if (o + 2 >= 0 && o + 2 < WINS) v4.z = slotval[o + 2];
            if (o + 3 >= 0 && o + 3 < WINS) v4.w = slotval[o + 3];
        }
        orow[c4] = v4;
    }
}

extern "C" void kernel_launch(void* const* d_in, const int* in_sizes, int n_in,
                              void* d_out, int out_size, void* d_ws, size_t ws_size,
                              hipStream_t stream)
{
    const float* X  = (const float*)d_in[0];
    const float* Wq = (const float*)d_in[1];
    const float* bq = (const float*)d_in[2];
    const float* Wk = (const float*)d_in[3];
    const float* bk = (const float*)d_in[4];
    const int* nnpg = (const int*)d_in[5];
    const int* nrel = (const int*)d_in[6];

    const int n = in_sizes[0] / NF;
    const int n_graphs = in_sizes[5];

    float* Qb = (float*)d_ws;                 // [n][256]
    float* Kb = Qb + (size_t)n * HD;          // [n][256]
    float* out = (float*)d_out;

    dim3 gg(n / GROWS, 2);
    qk_gemm_kernel<<<gg, 512, 0, stream>>>(X, Wq, bq, Wk, bk, Qb, Kb, n);

    attn_topk_kernel<<<n, 256, 0, stream>>>(Qb, Kb, nnpg, n_graphs, nrel, out, n);
}